// Round 1
// baseline (249.491 us; speedup 1.0000x reference)
//
#include <hip/hip_runtime.h>

// ---------------------------------------------------------------------------
// Linear attention (causal, phi = elu+1), B=2 T=2048 H=16 dk=64 D=1024.
// Chunked formulation, chunk C=64:
//   intra: O_i += sum_{j<=i in chunk} (q_i.k_j) v_j  = causal(Q K^T) V
//   inter: O_i += q_i . KVpref(chunk)                (exclusive chunk prefix)
//   z_i   = rowsum(causal(Q K^T)) + q_i . kpref(chunk)
// All GEMM-shaped pieces on bf16 MFMA 16x16x32, fp32 accum.
// ---------------------------------------------------------------------------

typedef float  f32x4   __attribute__((ext_vector_type(4)));
typedef __bf16 bf16x8  __attribute__((ext_vector_type(8)));
typedef short  short8v __attribute__((ext_vector_type(8)));
typedef short  short4v __attribute__((ext_vector_type(4)));

static __device__ __forceinline__ short f2bf(float f) {
    unsigned u = __float_as_uint(f);
    u += 0x7FFFu + ((u >> 16) & 1u);          // RNE
    return (short)(u >> 16);
}
static __device__ __forceinline__ float bf2f(short s) {
    return __uint_as_float(((unsigned)(unsigned short)s) << 16);
}
static __device__ __forceinline__ float phi(float x) {   // elu(x)+1
    return x > 0.f ? x + 1.f : __expf(x);
}

#define LDA 40   // 128x32 tile leading dim (pad: 20-bank rotation -> free 2-way)
#define LDT 72   // 64x64 tile leading dim  (pad:  4-bank rotation -> free 2-way)

// ---------------- Kernel 1: fused QKV projection GEMM ----------------------
// C[4096,3072] = x @ [Wq;Wk;Wv]^T (+bias), phi on Q/K, out layout [BH][T][64] bf16.
__global__ __launch_bounds__(256) void gemm_qkv(
    const float* __restrict__ x,
    const float* __restrict__ Wq, const float* __restrict__ bq,
    const float* __restrict__ Wk, const float* __restrict__ bk,
    const float* __restrict__ Wv, const float* __restrict__ bv,
    short* __restrict__ Qb, short* __restrict__ Kb, short* __restrict__ Vb)
{
    __shared__ short As[128 * LDA];
    __shared__ short Bs[128 * LDA];
    const int tid = threadIdx.x;
    const int bm = blockIdx.x, bn = blockIdx.y;         // 32 x 24
    const int wsel  = bn >> 3;                          // 0=Q 1=K 2=V
    const int nloc0 = (bn & 7) << 7;                    // row offset in W
    const float* __restrict__ W    = (wsel == 0) ? Wq : (wsel == 1) ? Wk : Wv;
    const float* __restrict__ bias = (wsel == 0) ? bq : (wsel == 1) ? bk : bv;
    const int m0 = bm << 7;

    const int wave = tid >> 6, lane = tid & 63;
    const int wm = (wave & 1) << 6, wn = (wave >> 1) << 6;
    const int l15 = lane & 15, quad = lane >> 4;

    f32x4 acc[4][4] = {};
    const int srow = tid >> 3;
    const int scol = (tid & 7) << 2;

    for (int k0 = 0; k0 < 1024; k0 += 32) {
        __syncthreads();
#pragma unroll
        for (int p = 0; p < 4; ++p) {
            const int r = srow + p * 32;
            f32x4 va = *(const f32x4*)(&x[(size_t)(m0 + r) * 1024 + k0 + scol]);
            f32x4 vb = *(const f32x4*)(&W[(size_t)(nloc0 + r) * 1024 + k0 + scol]);
            short4v sa, sb;
#pragma unroll
            for (int q2 = 0; q2 < 4; ++q2) { sa[q2] = f2bf(va[q2]); sb[q2] = f2bf(vb[q2]); }
            *(short4v*)&As[r * LDA + scol] = sa;
            *(short4v*)&Bs[r * LDA + scol] = sb;
        }
        __syncthreads();
        bf16x8 a[4], b[4];
#pragma unroll
        for (int i = 0; i < 4; ++i) a[i] = *(const bf16x8*)&As[(wm + i * 16 + l15) * LDA + quad * 8];
#pragma unroll
        for (int j = 0; j < 4; ++j) b[j] = *(const bf16x8*)&Bs[(wn + j * 16 + l15) * LDA + quad * 8];
#pragma unroll
        for (int i = 0; i < 4; ++i)
#pragma unroll
            for (int j = 0; j < 4; ++j)
                acc[i][j] = __builtin_amdgcn_mfma_f32_16x16x32_bf16(a[i], b[j], acc[i][j], 0, 0, 0);
    }

#pragma unroll
    for (int i = 0; i < 4; ++i) {
#pragma unroll
        for (int j = 0; j < 4; ++j) {
            const int col = nloc0 + wn + j * 16 + l15;   // 0..1023 within this W
            const float bv_ = bias[col];
#pragma unroll
            for (int r = 0; r < 4; ++r) {
                const int row = m0 + wm + i * 16 + quad * 4 + r;  // C/D: row=quad*4+reg, col=lane&15
                const float v = acc[i][j][r] + bv_;
                const int bb = row >> 11, t = row & 2047;
                const int h = col >> 6, d = col & 63;
                const size_t off = ((((size_t)(bb * 16 + h)) << 11) + t) * 64 + d;
                if (wsel == 0)      Qb[off] = f2bf(phi(v));
                else if (wsel == 1) Kb[off] = f2bf(phi(v));
                else                Vb[off] = f2bf(v);
            }
        }
    }
}

// ---------------- Kernel 2: per-chunk KV state: KV_c = K_c^T V_c, ksum_c ---
__global__ __launch_bounds__(256) void chunk_sums(
    const short* __restrict__ Kb, const short* __restrict__ Vb,
    float* __restrict__ KVsum, float* __restrict__ ksum)
{
    __shared__ short KT[64 * LDT];   // K^T : [d][t]
    __shared__ short VT[64 * LDT];   // V^T : [e][t]
    const int c = blockIdx.x, bh = blockIdx.y;
    const int tid = threadIdx.x;
    const int w = tid >> 6, lane = tid & 63, l15 = lane & 15, quad = lane >> 4;
    const size_t cbase = (((size_t)bh << 11) + (c << 6)) * 64;
    const short* __restrict__ Kc = Kb + cbase;
    const short* __restrict__ Vc = Vb + cbase;

#pragma unroll
    for (int p = 0; p < 2; ++p) {
        const int t = (tid >> 3) + p * 32;
        const int e0 = (tid & 7) << 3;
        short8v kv = *(const short8v*)&Kc[t * 64 + e0];
        short8v vv = *(const short8v*)&Vc[t * 64 + e0];
#pragma unroll
        for (int jj = 0; jj < 8; ++jj) {
            KT[(e0 + jj) * LDT + t] = kv[jj];
            VT[(e0 + jj) * LDT + t] = vv[jj];
        }
    }
    __syncthreads();

    f32x4 acc[4] = {};
#pragma unroll
    for (int k0 = 0; k0 < 64; k0 += 32) {
        bf16x8 a = *(const bf16x8*)&KT[(w * 16 + l15) * LDT + k0 + quad * 8];
#pragma unroll
        for (int tj = 0; tj < 4; ++tj) {
            bf16x8 bfr = *(const bf16x8*)&VT[(tj * 16 + l15) * LDT + k0 + quad * 8];
            acc[tj] = __builtin_amdgcn_mfma_f32_16x16x32_bf16(a, bfr, acc[tj], 0, 0, 0);
        }
    }
    float* __restrict__ outp = KVsum + (((size_t)bh * 32) + c) * 4096;
#pragma unroll
    for (int tj = 0; tj < 4; ++tj)
#pragma unroll
        for (int r = 0; r < 4; ++r)
            outp[(w * 16 + quad * 4 + r) * 64 + tj * 16 + l15] = acc[tj][r];

    if (tid < 64) {
        float s = 0.f;
        for (int t = 0; t < 64; ++t) s += bf2f(KT[tid * LDT + t]);
        ksum[(((size_t)bh * 32) + c) * 64 + tid] = s;
    }
}

// ---------------- Kernel 3: exclusive prefix scan over 32 chunks -----------
// Writes KV prefix TRANSPOSED ([e][d], bf16) so kernel 4's B-frag reads are contiguous.
__global__ __launch_bounds__(256) void scan_chunks(
    const float* __restrict__ KVsum, const float* __restrict__ ksum,
    short* __restrict__ KVprefT, float* __restrict__ kpref)
{
    const int bh = blockIdx.x, tid = threadIdx.x;
    float run[16];
#pragma unroll
    for (int ii = 0; ii < 16; ++ii) run[ii] = 0.f;
    for (int cc = 0; cc < 32; ++cc) {
        const float* __restrict__ in = KVsum + (((size_t)bh * 32) + cc) * 4096;
        short* __restrict__ op = KVprefT + (((size_t)bh * 32) + cc) * 4096;
#pragma unroll
        for (int ii = 0; ii < 16; ++ii) {
            const int o = tid + ii * 256;       // o = e*64 + d  (transposed out)
            const int d = o & 63, e = o >> 6;
            op[o] = f2bf(run[ii]);              // exclusive
            run[ii] += in[d * 64 + e];
        }
    }
    if (tid < 64) {
        float r2 = 0.f;
        for (int cc = 0; cc < 32; ++cc) {
            kpref[(((size_t)bh * 32) + cc) * 64 + tid] = r2;
            r2 += ksum[(((size_t)bh * 32) + cc) * 64 + tid];
        }
    }
}

// ---------------- Kernel 4: per-chunk attention ----------------------------
__global__ __launch_bounds__(256) void attn_chunk(
    const short* __restrict__ Qb, const short* __restrict__ Kb, const short* __restrict__ Vb,
    const short* __restrict__ KVprefT, const float* __restrict__ kpref,
    short* __restrict__ attn)
{
    __shared__ short Qs[64 * LDT];
    __shared__ short KS[64 * LDT];   // K, then overwritten with masked S
    __shared__ short VT[64 * LDT];   // V^T
    __shared__ short KVT[64 * LDT];  // KVpref^T ([e][d])
    __shared__ float kp[64];
    __shared__ float zinv[64];
    const int c = blockIdx.x, bh = blockIdx.y;
    const int bb = bh >> 4, h = bh & 15;
    const int tid = threadIdx.x;
    const int w = tid >> 6, lane = tid & 63, l15 = lane & 15, quad = lane >> 4;
    const size_t cbase = (((size_t)bh << 11) + (c << 6)) * 64;
    const short* __restrict__ Qc = Qb + cbase;
    const short* __restrict__ Kc = Kb + cbase;
    const short* __restrict__ Vc = Vb + cbase;
    const short* __restrict__ KVc = KVprefT + (((size_t)bh * 32) + c) * 4096;

#pragma unroll
    for (int p = 0; p < 2; ++p) {
        const int t = (tid >> 3) + p * 32;
        const int e0 = (tid & 7) << 3;
        *(short8v*)&Qs[t * LDT + e0]  = *(const short8v*)&Qc[t * 64 + e0];
        *(short8v*)&KS[t * LDT + e0]  = *(const short8v*)&Kc[t * 64 + e0];
        *(short8v*)&KVT[t * LDT + e0] = *(const short8v*)&KVc[t * 64 + e0];
        short8v vv = *(const short8v*)&Vc[t * 64 + e0];
#pragma unroll
        for (int jj = 0; jj < 8; ++jj) VT[(e0 + jj) * LDT + t] = vv[jj];
    }
    if (tid < 64) kp[tid] = kpref[(((size_t)bh * 32) + c) * 64 + tid];
    __syncthreads();

    // S = Q K^T (wave w owns rows w*16..w*16+15)
    f32x4 sacc[4] = {};
#pragma unroll
    for (int k0 = 0; k0 < 64; k0 += 32) {
        bf16x8 a = *(const bf16x8*)&Qs[(w * 16 + l15) * LDT + k0 + quad * 8];
#pragma unroll
        for (int tj = 0; tj < 4; ++tj) {
            bf16x8 bfr = *(const bf16x8*)&KS[(tj * 16 + l15) * LDT + k0 + quad * 8];
            sacc[tj] = __builtin_amdgcn_mfma_f32_16x16x32_bf16(a, bfr, sacc[tj], 0, 0, 0);
        }
    }
    __syncthreads();   // all waves done reading K before S overwrites it
#pragma unroll
    for (int tj = 0; tj < 4; ++tj)
#pragma unroll
        for (int r = 0; r < 4; ++r) {
            const int i = w * 16 + quad * 4 + r;
            const int j = tj * 16 + l15;
            KS[i * LDT + j] = f2bf(j <= i ? sacc[tj][r] : 0.f);  // causal incl. diagonal
        }
    __syncthreads();
    if (tid < 64) {
        const int i = tid;
        float z = 0.f;
        for (int j = 0; j <= i; ++j) z += bf2f(KS[i * LDT + j]);
        for (int d = 0; d < 64; ++d) z += bf2f(Qs[i * LDT + d]) * kp[d];
        zinv[i] = 1.f / (z + 1e-6f);
    }
    __syncthreads();

    // O = S V + Q KVpref
    f32x4 oacc[4] = {};
#pragma unroll
    for (int k0 = 0; k0 < 64; k0 += 32) {
        bf16x8 a1 = *(const bf16x8*)&KS[(w * 16 + l15) * LDT + k0 + quad * 8];
        bf16x8 a2 = *(const bf16x8*)&Qs[(w * 16 + l15) * LDT + k0 + quad * 8];
#pragma unroll
        for (int tj = 0; tj < 4; ++tj) {
            bf16x8 b1 = *(const bf16x8*)&VT[(tj * 16 + l15) * LDT + k0 + quad * 8];
            bf16x8 b2 = *(const bf16x8*)&KVT[(tj * 16 + l15) * LDT + k0 + quad * 8];
            oacc[tj] = __builtin_amdgcn_mfma_f32_16x16x32_bf16(a1, b1, oacc[tj], 0, 0, 0);
            oacc[tj] = __builtin_amdgcn_mfma_f32_16x16x32_bf16(a2, b2, oacc[tj], 0, 0, 0);
        }
    }
#pragma unroll
    for (int tj = 0; tj < 4; ++tj)
#pragma unroll
        for (int r = 0; r < 4; ++r) {
            const int i = w * 16 + quad * 4 + r;
            const int e = tj * 16 + l15;
            const int m = (bb << 11) + (c << 6) + i;       // b*2048 + t
            attn[(size_t)m * 1024 + (h << 6) + e] = f2bf(oacc[tj][r] * zinv[i]);
        }
}

// ---------------- Kernel 5: output projection GEMM -------------------------
__global__ __launch_bounds__(256) void gemm_out(
    const short* __restrict__ attn, const float* __restrict__ Wo,
    const float* __restrict__ bo, float* __restrict__ outp)
{
    __shared__ short As[128 * LDA];
    __shared__ short Bs[128 * LDA];
    const int tid = threadIdx.x;
    const int bm = blockIdx.x, bn = blockIdx.y;      // 32 x 8
    const int m0 = bm << 7, n0 = bn << 7;
    const int wave = tid >> 6, lane = tid & 63;
    const int wm = (wave & 1) << 6, wn = (wave >> 1) << 6;
    const int l15 = lane & 15, quad = lane >> 4;

    f32x4 acc[4][4] = {};
    const int arow = tid >> 2, acol = (tid & 3) << 3;   // bf16 A: 64 rows/pass x2
    const int brow = tid >> 3, bcol = (tid & 7) << 2;   // fp32 B: 32 rows/pass x4

    for (int k0 = 0; k0 < 1024; k0 += 32) {
        __syncthreads();
#pragma unroll
        for (int p = 0; p < 2; ++p) {
            const int r = arow + p * 64;
            *(short8v*)&As[r * LDA + acol] =
                *(const short8v*)&attn[(size_t)(m0 + r) * 1024 + k0 + acol];
        }
#pragma unroll
        for (int p = 0; p < 4; ++p) {
            const int r = brow + p * 32;
            f32x4 vb = *(const f32x4*)&Wo[(size_t)(n0 + r) * 1024 + k0 + bcol];
            short4v sb;
#pragma unroll
            for (int q2 = 0; q2 < 4; ++q2) sb[q2] = f2bf(vb[q2]);
            *(short4v*)&Bs[r * LDA + bcol] = sb;
        }
        __syncthreads();
        bf16x8 a[4], b[4];
#pragma unroll
        for (int i = 0; i < 4; ++i) a[i] = *(const bf16x8*)&As[(wm + i * 16 + l15) * LDA + quad * 8];
#pragma unroll
        for (int j = 0; j < 4; ++j) b[j] = *(const bf16x8*)&Bs[(wn + j * 16 + l15) * LDA + quad * 8];
#pragma unroll
        for (int i = 0; i < 4; ++i)
#pragma unroll
            for (int j = 0; j < 4; ++j)
                acc[i][j] = __builtin_amdgcn_mfma_f32_16x16x32_bf16(a[i], b[j], acc[i][j], 0, 0, 0);
    }

#pragma unroll
    for (int i = 0; i < 4; ++i)
#pragma unroll
        for (int j = 0; j < 4; ++j) {
            const int col = n0 + wn + j * 16 + l15;
            const float bv_ = bo[col];
#pragma unroll
            for (int r = 0; r < 4; ++r) {
                const int row = m0 + wm + i * 16 + quad * 4 + r;
                outp[(size_t)row * 1024 + col] = acc[i][j][r] + bv_;
            }
        }
}

// ---------------------------------------------------------------------------
extern "C" void kernel_launch(void* const* d_in, const int* in_sizes, int n_in,
                              void* d_out, int out_size, void* d_ws, size_t ws_size,
                              hipStream_t stream)
{
    const float* x  = (const float*)d_in[0];
    const float* Wq = (const float*)d_in[1];
    const float* bq = (const float*)d_in[2];
    const float* Wk = (const float*)d_in[3];
    const float* bk = (const float*)d_in[4];
    const float* Wv = (const float*)d_in[5];
    const float* bv = (const float*)d_in[6];
    const float* Wo = (const float*)d_in[7];
    const float* bo = (const float*)d_in[8];

    char* ws = (char*)d_ws;
    short* Qb      = (short*)(ws + 0);          //  8 MB  [BH][T][64] bf16
    short* Kb      = (short*)(ws + 8388608);    //  8 MB
    short* Vb      = (short*)(ws + 16777216);   //  8 MB
    short* attn    = (short*)(ws + 25165824);   //  8 MB  [4096][1024] bf16
    float* KVsum   = (float*)(ws + 33554432);   // 16 MB  [BH][32][64*64] fp32
    short* KVprefT = (short*)(ws + 50331648);   //  8 MB  [BH][32][e*64+d] bf16
    float* ksum    = (float*)(ws + 58720256);   // 256 KB
    float* kpref   = (float*)(ws + 58982400);   // 256 KB
    float* outp    = (float*)d_out;

    gemm_qkv  <<<dim3(32, 24), 256, 0, stream>>>(x, Wq, bq, Wk, bk, Wv, bv, Qb, Kb, Vb);
    chunk_sums<<<dim3(32, 32), 256, 0, stream>>>(Kb, Vb, KVsum, ksum);
    scan_chunks<<<32, 256, 0, stream>>>(KVsum, ksum, KVprefT, kpref);
    attn_chunk<<<dim3(32, 32), 256, 0, stream>>>(Qb, Kb, Vb, KVprefT, kpref, attn);
    gemm_out  <<<dim3(32, 8), 256, 0, stream>>>(attn, Wo, bo, outp);
}

// Round 2
// 169.157 us; speedup vs baseline: 1.4749x; 1.4749x over previous
//
#include <hip/hip_runtime.h>

// ---------------------------------------------------------------------------
// Linear attention (causal, phi = elu+1), B=2 T=2048 H=16 dk=64 D=1024.
// Chunked (C=64): intra-chunk causal(QK^T)V via MFMA, inter-chunk exclusive
// prefix of per-chunk K^T V states. All inputs pre-converted to bf16; both
// big GEMMs use the m97 structure (global_load_lds dwordx4, 128x128 tile).
// ---------------------------------------------------------------------------

typedef float  f32x4   __attribute__((ext_vector_type(4)));
typedef __bf16 bf16x8  __attribute__((ext_vector_type(8)));
typedef short  short8v __attribute__((ext_vector_type(8)));
typedef short  short4v __attribute__((ext_vector_type(4)));

static __device__ __forceinline__ short f2bf(float f) {
    unsigned u = __float_as_uint(f);
    u += 0x7FFFu + ((u >> 16) & 1u);          // RNE
    return (short)(u >> 16);
}
static __device__ __forceinline__ float bf2f(short s) {
    return __uint_as_float(((unsigned)(unsigned short)s) << 16);
}
static __device__ __forceinline__ float phi(float x) {   // elu(x)+1
    return x > 0.f ? x + 1.f : __expf(x);
}
static __device__ __forceinline__ void gl_lds16(const short* g, short* l) {
    __builtin_amdgcn_global_load_lds(
        (const __attribute__((address_space(1))) void*)g,
        (__attribute__((address_space(3))) void*)l, 16, 0, 0);
}

#define LDT 72   // 64x64 tile leading dim (4-bank rotation -> free 2-way)

// ---------------- Kernel 0: fp32 -> bf16 conversion ------------------------
// blocks: [0,2048) x ; [2048,2560) Wq ; [2560,3072) Wk ; [3072,3584) Wv ;
//         [3584,4096) Wo.  2048 elems/block.
__global__ __launch_bounds__(256) void convert_bf16(
    const float* __restrict__ x,  const float* __restrict__ Wq,
    const float* __restrict__ Wk, const float* __restrict__ Wv,
    const float* __restrict__ Wo,
    short* __restrict__ xb,  short* __restrict__ Wqb,
    short* __restrict__ Wkb, short* __restrict__ Wvb, short* __restrict__ Wob)
{
    const int blk = blockIdx.x;
    const float* src; short* dst; size_t base;
    if (blk < 2048)      { src = x;  dst = xb;  base = (size_t)blk * 2048; }
    else if (blk < 2560) { src = Wq; dst = Wqb; base = (size_t)(blk - 2048) * 2048; }
    else if (blk < 3072) { src = Wk; dst = Wkb; base = (size_t)(blk - 2560) * 2048; }
    else if (blk < 3584) { src = Wv; dst = Wvb; base = (size_t)(blk - 3072) * 2048; }
    else                 { src = Wo; dst = Wob; base = (size_t)(blk - 3584) * 2048; }
    const size_t o = base + (size_t)threadIdx.x * 8;
    f32x4 v0 = *(const f32x4*)&src[o];
    f32x4 v1 = *(const f32x4*)&src[o + 4];
    short8v s;
#pragma unroll
    for (int m = 0; m < 4; ++m) { s[m] = f2bf(v0[m]); s[m + 4] = f2bf(v1[m]); }
    *(short8v*)&dst[o] = s;
}

// ---------------- Kernel 1: fused QKV projection GEMM (m97 structure) ------
// out layout [B,T,H*64] = [4096][1024] bf16 per Q/K/V; phi fused on Q/K.
__global__ __launch_bounds__(256) void gemm_qkv(
    const short* __restrict__ xb,
    const short* __restrict__ Wqb, const short* __restrict__ Wkb,
    const short* __restrict__ Wvb,
    const float* __restrict__ bq, const float* __restrict__ bk,
    const float* __restrict__ bv,
    short* __restrict__ Qb, short* __restrict__ Kb, short* __restrict__ Vb)
{
    __shared__ short As[128 * 32];
    __shared__ short Bs[128 * 32];
    const int tid = threadIdx.x;
    const int bm = blockIdx.x, bn = blockIdx.y;      // 32 x 24
    const int wsel = bn >> 3;                        // 0=Q 1=K 2=V
    const int n0 = (bn & 7) << 7;
    const short* __restrict__ W    = (wsel == 0) ? Wqb : (wsel == 1) ? Wkb : Wvb;
    const float* __restrict__ bias = (wsel == 0) ? bq  : (wsel == 1) ? bk  : bv;
    short* __restrict__ Ob         = (wsel == 0) ? Qb  : (wsel == 1) ? Kb  : Vb;
    const int m0 = bm << 7;
    const int wave = tid >> 6, lane = tid & 63;
    const int wm = (wave & 1) << 6, wn = (wave >> 1) << 6;
    const int l15 = lane & 15, quad = lane >> 4;

    // staging: 8 chunks of 16 rows x 32 cols; wave w owns chunks 2w, 2w+1
    const int ch0 = wave * 2, ch1 = ch0 + 1;
    const int lrow = lane >> 2, lcol = (lane & 3) << 3;
    const short* ga0 = xb + (size_t)(m0 + ch0 * 16 + lrow) * 1024 + lcol;
    const short* ga1 = xb + (size_t)(m0 + ch1 * 16 + lrow) * 1024 + lcol;
    const short* gb0 = W  + (size_t)(n0 + ch0 * 16 + lrow) * 1024 + lcol;
    const short* gb1 = W  + (size_t)(n0 + ch1 * 16 + lrow) * 1024 + lcol;
    short* la0 = &As[ch0 * 512];
    short* la1 = &As[ch1 * 512];
    short* lb0 = &Bs[ch0 * 512];
    short* lb1 = &Bs[ch1 * 512];

    f32x4 acc[4][4] = {};
    for (int k0 = 0; k0 < 1024; k0 += 32) {
        __syncthreads();
        gl_lds16(ga0 + k0, la0);
        gl_lds16(ga1 + k0, la1);
        gl_lds16(gb0 + k0, lb0);
        gl_lds16(gb1 + k0, lb1);
        __syncthreads();
        bf16x8 a[4], b[4];
#pragma unroll
        for (int i = 0; i < 4; ++i) a[i] = *(const bf16x8*)&As[(wm + i * 16 + l15) * 32 + quad * 8];
#pragma unroll
        for (int j = 0; j < 4; ++j) b[j] = *(const bf16x8*)&Bs[(wn + j * 16 + l15) * 32 + quad * 8];
#pragma unroll
        for (int i = 0; i < 4; ++i)
#pragma unroll
            for (int j = 0; j < 4; ++j)
                acc[i][j] = __builtin_amdgcn_mfma_f32_16x16x32_bf16(a[i], b[j], acc[i][j], 0, 0, 0);
    }

#pragma unroll
    for (int i = 0; i < 4; ++i)
#pragma unroll
        for (int j = 0; j < 4; ++j) {
            const int col = n0 + wn + j * 16 + l15;     // 0..1023 = h*64+d
            const float bv_ = bias[col];
#pragma unroll
            for (int r = 0; r < 4; ++r) {
                const int row = m0 + wm + i * 16 + quad * 4 + r;   // b*2048+t
                float v = acc[i][j][r] + bv_;
                if (wsel < 2) v = phi(v);
                Ob[(size_t)row * 1024 + col] = f2bf(v);
            }
        }
}

// ---------------- Kernel 2: per-chunk KV state: KV_c = K_c^T V_c, ksum_c ---
__global__ __launch_bounds__(256) void chunk_sums(
    const short* __restrict__ Kb, const short* __restrict__ Vb,
    short* __restrict__ KVsum, float* __restrict__ ksum)
{
    __shared__ short KT[64 * LDT];   // K^T : [d][t]
    __shared__ short VT[64 * LDT];   // V^T : [e][t]
    __shared__ float pS[256];
    const int c = blockIdx.x, bh = blockIdx.y;
    const int b = bh >> 4, h = bh & 15;
    const int tid = threadIdx.x;
    const int w = tid >> 6, lane = tid & 63, l15 = lane & 15, quad = lane >> 4;
    const size_t rowbase = (size_t)b * 2048 + c * 64;

#pragma unroll
    for (int p = 0; p < 2; ++p) {
        const int t = (tid >> 3) + p * 32;
        const int e0 = (tid & 7) << 3;
        const size_t g = (rowbase + t) * 1024 + h * 64 + e0;
        short8v kv = *(const short8v*)&Kb[g];
        short8v vv = *(const short8v*)&Vb[g];
#pragma unroll
        for (int jj = 0; jj < 8; ++jj) {
            KT[(e0 + jj) * LDT + t] = kv[jj];
            VT[(e0 + jj) * LDT + t] = vv[jj];
        }
    }
    __syncthreads();

    f32x4 acc[4] = {};
#pragma unroll
    for (int k0 = 0; k0 < 64; k0 += 32) {
        bf16x8 a = *(const bf16x8*)&KT[(w * 16 + l15) * LDT + k0 + quad * 8];
#pragma unroll
        for (int tj = 0; tj < 4; ++tj) {
            bf16x8 bfr = *(const bf16x8*)&VT[(tj * 16 + l15) * LDT + k0 + quad * 8];
            acc[tj] = __builtin_amdgcn_mfma_f32_16x16x32_bf16(a, bfr, acc[tj], 0, 0, 0);
        }
    }
    short* __restrict__ outp = KVsum + (((size_t)bh * 32) + c) * 4096;
#pragma unroll
    for (int tj = 0; tj < 4; ++tj)
#pragma unroll
        for (int r = 0; r < 4; ++r)
            outp[(w * 16 + quad * 4 + r) * 64 + tj * 16 + l15] = f2bf(acc[tj][r]);

    {   // ksum partials: thread = (part, d)
        const int d = tid & 63, part = tid >> 6;
        short8v k1 = *(const short8v*)&KT[d * LDT + part * 16];
        short8v k2 = *(const short8v*)&KT[d * LDT + part * 16 + 8];
        float s = 0.f;
#pragma unroll
        for (int m = 0; m < 8; ++m) s += bf2f(k1[m]) + bf2f(k2[m]);
        pS[part * 64 + d] = s;
    }
    __syncthreads();
    if (tid < 64)
        ksum[(((size_t)bh * 32) + c) * 64 + tid] =
            pS[tid] + pS[tid + 64] + pS[tid + 128] + pS[tid + 192];
}

// ---------------- Kernel 3: exclusive prefix scan over 32 chunks -----------
// KVsum / KVpref both in [d][e] order; fully coalesced (one thread per elem).
__global__ __launch_bounds__(256) void scan_chunks(
    const short* __restrict__ KVsum, const float* __restrict__ ksum,
    short* __restrict__ KVpref, float* __restrict__ kpref)
{
    const int bh = blockIdx.y;
    const int o = blockIdx.x * 256 + threadIdx.x;     // 16 x 256 = 4096
    float run = 0.f;
    size_t base = (size_t)bh * 32 * 4096 + o;
    for (int cc = 0; cc < 32; ++cc) {
        KVpref[base] = f2bf(run);                     // exclusive
        run += bf2f(KVsum[base]);
        base += 4096;
    }
    if (blockIdx.x == 0 && threadIdx.x < 64) {
        float vals[32];
        const size_t kb = (size_t)bh * 32 * 64 + threadIdx.x;
#pragma unroll
        for (int cc = 0; cc < 32; ++cc) vals[cc] = ksum[kb + (size_t)cc * 64];
        float r2 = 0.f;
#pragma unroll
        for (int cc = 0; cc < 32; ++cc) { kpref[kb + (size_t)cc * 64] = r2; r2 += vals[cc]; }
    }
}

// ---------------- Kernel 4: per-chunk attention ----------------------------
__global__ __launch_bounds__(256) void attn_chunk(
    const short* __restrict__ Qb, const short* __restrict__ Kb,
    const short* __restrict__ Vb, const short* __restrict__ KVpref,
    const float* __restrict__ kpref, short* __restrict__ attnb)
{
    __shared__ short Qs[64 * LDT];
    __shared__ short KS[64 * LDT];   // K, then overwritten with masked S
    __shared__ short VT[64 * LDT];   // V^T  [e][t]
    __shared__ short KVT[64 * LDT];  // KVpref^T [e][d]
    const int c = blockIdx.x, bh = blockIdx.y;
    const int b = bh >> 4, h = bh & 15;
    const int tid = threadIdx.x;
    const int w = tid >> 6, lane = tid & 63, l15 = lane & 15, quad = lane >> 4;
    const size_t rowbase = (size_t)b * 2048 + c * 64;
    const short* __restrict__ KVc = KVpref + (((size_t)bh * 32) + c) * 4096;

#pragma unroll
    for (int p = 0; p < 2; ++p) {
        const int t = (tid >> 3) + p * 32;             // also plays "d" for KVpref
        const int e0 = (tid & 7) << 3;
        const size_t g = (rowbase + t) * 1024 + h * 64 + e0;
        *(short8v*)&Qs[t * LDT + e0] = *(const short8v*)&Qb[g];
        *(short8v*)&KS[t * LDT + e0] = *(const short8v*)&Kb[g];
        short8v vv = *(const short8v*)&Vb[g];
        short8v pv = *(const short8v*)&KVc[t * 64 + e0];
#pragma unroll
        for (int jj = 0; jj < 8; ++jj) {
            VT[(e0 + jj) * LDT + t]  = vv[jj];
            KVT[(e0 + jj) * LDT + t] = pv[jj];
        }
    }
    __syncthreads();

    // S = Q K^T (wave w owns rows w*16..w*16+15)
    f32x4 sacc[4] = {};
#pragma unroll
    for (int k0 = 0; k0 < 64; k0 += 32) {
        bf16x8 a = *(const bf16x8*)&Qs[(w * 16 + l15) * LDT + k0 + quad * 8];
#pragma unroll
        for (int tj = 0; tj < 4; ++tj) {
            bf16x8 bfr = *(const bf16x8*)&KS[(tj * 16 + l15) * LDT + k0 + quad * 8];
            sacc[tj] = __builtin_amdgcn_mfma_f32_16x16x32_bf16(a, bfr, sacc[tj], 0, 0, 0);
        }
    }

    // z per (quad, r) via masked rowsum of sacc + q.kpref, 16-lane butterfly
    f32x4 kp4 = *(const f32x4*)&kpref[(((size_t)bh * 32) + c) * 64 + l15 * 4];
    float zinv[4];
#pragma unroll
    for (int r = 0; r < 4; ++r) {
        const int i = w * 16 + quad * 4 + r;
        float p = 0.f;
#pragma unroll
        for (int tj = 0; tj < 4; ++tj)
            if (tj * 16 + l15 <= i) p += sacc[tj][r];
        short4v q4 = *(const short4v*)&Qs[i * LDT + l15 * 4];
#pragma unroll
        for (int m = 0; m < 4; ++m) p += bf2f(q4[m]) * kp4[m];
        p += __shfl_xor(p, 1);
        p += __shfl_xor(p, 2);
        p += __shfl_xor(p, 4);
        p += __shfl_xor(p, 8);
        zinv[r] = 1.f / (p + 1e-6f);
    }

    __syncthreads();   // all waves done reading KS-as-K
#pragma unroll
    for (int tj = 0; tj < 4; ++tj)
#pragma unroll
        for (int r = 0; r < 4; ++r) {
            const int i = w * 16 + quad * 4 + r;
            const int j = tj * 16 + l15;
            KS[i * LDT + j] = f2bf(j <= i ? sacc[tj][r] : 0.f);
        }
    __syncthreads();

    // O = causal(S) V + Q KVpref
    f32x4 oacc[4] = {};
#pragma unroll
    for (int k0 = 0; k0 < 64; k0 += 32) {
        bf16x8 a1 = *(const bf16x8*)&KS[(w * 16 + l15) * LDT + k0 + quad * 8];
        bf16x8 a2 = *(const bf16x8*)&Qs[(w * 16 + l15) * LDT + k0 + quad * 8];
#pragma unroll
        for (int tj = 0; tj < 4; ++tj) {
            bf16x8 b1 = *(const bf16x8*)&VT[(tj * 16 + l15) * LDT + k0 + quad * 8];
            bf16x8 b2 = *(const bf16x8*)&KVT[(tj * 16 + l15) * LDT + k0 + quad * 8];
            oacc[tj] = __builtin_amdgcn_mfma_f32_16x16x32_bf16(a1, b1, oacc[tj], 0, 0, 0);
            oacc[tj] = __builtin_amdgcn_mfma_f32_16x16x32_bf16(a2, b2, oacc[tj], 0, 0, 0);
        }
    }
#pragma unroll
    for (int tj = 0; tj < 4; ++tj)
#pragma unroll
        for (int r = 0; r < 4; ++r) {
            const int i = w * 16 + quad * 4 + r;
            const int e = tj * 16 + l15;
            attnb[(rowbase + i) * 1024 + h * 64 + e] = f2bf(oacc[tj][r] * zinv[r]);
        }
}

// ---------------- Kernel 5: output projection GEMM (m97 structure) ---------
__global__ __launch_bounds__(256) void gemm_out(
    const short* __restrict__ attnb, const short* __restrict__ Wob,
    const float* __restrict__ bo, float* __restrict__ outp)
{
    __shared__ short As[128 * 32];
    __shared__ short Bs[128 * 32];
    const int tid = threadIdx.x;
    const int bm = blockIdx.x, bn = blockIdx.y;      // 32 x 8
    const int m0 = bm << 7, n0 = bn << 7;
    const int wave = tid >> 6, lane = tid & 63;
    const int wm = (wave & 1) << 6, wn = (wave >> 1) << 6;
    const int l15 = lane & 15, quad = lane >> 4;

    const int ch0 = wave * 2, ch1 = ch0 + 1;
    const int lrow = lane >> 2, lcol = (lane & 3) << 3;
    const short* ga0 = attnb + (size_t)(m0 + ch0 * 16 + lrow) * 1024 + lcol;
    const short* ga1 = attnb + (size_t)(m0 + ch1 * 16 + lrow) * 1024 + lcol;
    const short* gb0 = Wob   + (size_t)(n0 + ch0 * 16 + lrow) * 1024 + lcol;
    const short* gb1 = Wob   + (size_t)(n0 + ch1 * 16 + lrow) * 1024 + lcol;
    short* la0 = &As[ch0 * 512];
    short* la1 = &As[ch1 * 512];
    short* lb0 = &Bs[ch0 * 512];
    short* lb1 = &Bs[ch1 * 512];

    f32x4 acc[4][4] = {};
    for (int k0 = 0; k0 < 1024; k0 += 32) {
        __syncthreads();
        gl_lds16(ga0 + k0, la0);
        gl_lds16(ga1 + k0, la1);
        gl_lds16(gb0 + k0, lb0);
        gl_lds16(gb1 + k0, lb1);
        __syncthreads();
        bf16x8 a[4], b[4];
#pragma unroll
        for (int i = 0; i < 4; ++i) a[i] = *(const bf16x8*)&As[(wm + i * 16 + l15) * 32 + quad * 8];
#pragma unroll
        for (int j = 0; j < 4; ++j) b[j] = *(const bf16x8*)&Bs[(wn + j * 16 + l15) * 32 + quad * 8];
#pragma unroll
        for (int i = 0; i < 4; ++i)
#pragma unroll
            for (int j = 0; j < 4; ++j)
                acc[i][j] = __builtin_amdgcn_mfma_f32_16x16x32_bf16(a[i], b[j], acc[i][j], 0, 0, 0);
    }

#pragma unroll
    for (int i = 0; i < 4; ++i)
#pragma unroll
        for (int j = 0; j < 4; ++j) {
            const int col = n0 + wn + j * 16 + l15;
            const float bv_ = bo[col];
#pragma unroll
            for (int r = 0; r < 4; ++r) {
                const int row = m0 + wm + i * 16 + quad * 4 + r;
                outp[(size_t)row * 1024 + col] = acc[i][j][r] + bv_;
            }
        }
}

// ---------------------------------------------------------------------------
extern "C" void kernel_launch(void* const* d_in, const int* in_sizes, int n_in,
                              void* d_out, int out_size, void* d_ws, size_t ws_size,
                              hipStream_t stream)
{
    const float* x  = (const float*)d_in[0];
    const float* Wq = (const float*)d_in[1];
    const float* bq = (const float*)d_in[2];
    const float* Wk = (const float*)d_in[3];
    const float* bk = (const float*)d_in[4];
    const float* Wv = (const float*)d_in[5];
    const float* bv = (const float*)d_in[6];
    const float* Wo = (const float*)d_in[7];
    const float* bo = (const float*)d_in[8];

    char* ws = (char*)d_ws;
    short* xb     = (short*)(ws + 0);          //  8 MB [4096][1024] bf16
    short* Wqb    = (short*)(ws + 8388608);    //  2 MB
    short* Wkb    = (short*)(ws + 10485760);   //  2 MB
    short* Wvb    = (short*)(ws + 12582912);   //  2 MB
    short* Wob    = (short*)(ws + 14680064);   //  2 MB
    short* Qb     = (short*)(ws + 16777216);   //  8 MB [4096][1024] bf16
    short* Kb     = (short*)(ws + 25165824);   //  8 MB
    short* Vb     = (short*)(ws + 33554432);   //  8 MB
    short* KVsum  = (short*)(ws + 41943040);   //  8 MB [bh][c][d*64+e] bf16
    short* attnb  = (short*)(ws + 41943040);   //  (alias: KVsum dead before attn written)
    short* KVpref = (short*)(ws + 50331648);   //  8 MB bf16, same layout as KVsum
    float* ksum   = (float*)(ws + 58720256);   // 256 KB
    float* kpref  = (float*)(ws + 58982400);   // 256 KB
    float* outp   = (float*)d_out;

    convert_bf16<<<4096, 256, 0, stream>>>(x, Wq, Wk, Wv, Wo, xb, Wqb, Wkb, Wvb, Wob);
    gemm_qkv   <<<dim3(32, 24), 256, 0, stream>>>(xb, Wqb, Wkb, Wvb, bq, bk, bv, Qb, Kb, Vb);
    chunk_sums <<<dim3(32, 32), 256, 0, stream>>>(Kb, Vb, KVsum, ksum);
    scan_chunks<<<dim3(16, 32), 256, 0, stream>>>(KVsum, ksum, KVpref, kpref);
    attn_chunk <<<dim3(32, 32), 256, 0, stream>>>(Qb, Kb, Vb, KVpref, kpref, attnb);
    gemm_out   <<<dim3(32, 8), 256, 0, stream>>>(attnb, Wob, bo, outp);
}